// Round 7
// baseline (83.047 us; speedup 1.0000x reference)
//
#include <hip/hip_runtime.h>
#include <utility>

#define NC 32     // num_capsule
#define DC 16     // dim_capsule
#define INC 144   // input capsules
#define IND 8     // input dim
#define NT 512    // threads per block
#define A2 2      // batch elements per block (share the W stream)

// LDS (halves): hat[32][2320] | lg[32][152] (x[2][144][8] fp16 overlaps, dead after H) | o_h[32][16]
#define HAT_BS 2320   // 1160 dwords == 8 mod 32 -> wave's 4 b-groups on disjoint bank octets
#define LG_S 152      // 76 dwords == 12 mod 32
#define LG_OFF (NC * HAT_BS)
#define OH_OFF (LG_OFF + NC * LG_S)      // 79104
#define SMEM_HALVES (OH_OFF + NC * DC)   // 79616
#define SMEM_BYTES (SMEM_HALVES * 2)     // 159232 <= 163840

typedef _Float16 h2 __attribute__((ext_vector_type(2)));
typedef _Float16 h4 __attribute__((ext_vector_type(4)));
typedef _Float16 h8 __attribute__((ext_vector_type(8)));
typedef float f4 __attribute__((ext_vector_type(4)));

union H8 { h8 v; h2 p[4]; };

// Compile-time loop: guarantees every array index is a constant GEP (rule #20).
template <class F, int... Is>
__device__ __forceinline__ void sfor_impl(F&& f, std::integer_sequence<int, Is...>) {
    (f(std::integral_constant<int, Is>{}), ...);
}
template <int N, class F>
__device__ __forceinline__ void sfor(F&& f) {
    sfor_impl((F&&)f, std::make_integer_sequence<int, N>{});
}

#if __has_builtin(__builtin_amdgcn_fdot2)
__device__ __forceinline__ float fdot2(h2 a, h2 b, float c) {
    return __builtin_amdgcn_fdot2(a, b, c, false);
}
#else
__device__ __forceinline__ float fdot2(h2 a, h2 b, float c) {
    return c + (float)a[0] * (float)b[0] + (float)a[1] * (float)b[1];
}
#endif

__global__ void convw_kernel(const float* __restrict__ W, _Float16* __restrict__ Wh) {
    int i = blockIdx.x * 256 + threadIdx.x;  // 147456 f4 groups
    f4 v = reinterpret_cast<const f4*>(W)[i];
    h4 h;
    h[0] = (_Float16)v[0]; h[1] = (_Float16)v[1];
    h[2] = (_Float16)v[2]; h[3] = (_Float16)v[3];
    reinterpret_cast<h4*>(Wh)[i] = h;
}

__device__ __forceinline__ float squash16(float s) {
    float n2 = s * s;
    n2 += __shfl_xor(n2, 1, 16);
    n2 += __shfl_xor(n2, 2, 16);
    n2 += __shfl_xor(n2, 4, 16);
    n2 += __shfl_xor(n2, 8, 16);
    return s * (n2 / ((1.0f + n2) * sqrtf(n2 + 1e-7f)));
}

// Routing for ONE batch element; hat fragments come from registers (hreg),
// the LDS hat copy serves only the B-pass. All hreg indices compile-time.
__device__ __forceinline__ void route_one(const h2 (&hreg)[72], float ocur,
                                          _Float16* hat, _Float16* lg, _Float16* o_h,
                                          float* __restrict__ out, int aout,
                                          int t, int b, int d) {
    // publish my (b,d) hat row + initial o to LDS (static indices)
    {
        _Float16* hp = hat + b * HAT_BS + d;
        sfor<INC>([&](auto C) {
            constexpr int c = C.value;
            hp[c * DC] = hreg[c >> 1][c & 1];
        });
        o_h[t] = (_Float16)ocur;
    }
    __syncthreads();

    float lgr[9];
    sfor<9>([&](auto K) { lgr[K.value] = 0.f; });  // fp32 logit master

    for (int it = 0; it < 2; ++it) {
        // ---- B-pass: logit[b][c] += o[b,:] . hat[b][c][:], c = d + 16k ----
        {
            H8 o0, o1;
            o0.v = *reinterpret_cast<const h8*>(o_h + b * DC);
            o1.v = *reinterpret_cast<const h8*>(o_h + b * DC + 8);
            sfor<9>([&](auto K) {
                constexpr int k = K.value;
                const int c = d + DC * k;
                const _Float16* hp = hat + b * HAT_BS + c * DC;
                H8 h0, h1;
                h0.v = *reinterpret_cast<const h8*>(hp);
                h1.v = *reinterpret_cast<const h8*>(hp + 8);
                float dot = fdot2(h0.p[0], o0.p[0], 0.f);
                dot = fdot2(h0.p[1], o0.p[1], dot);
                dot = fdot2(h0.p[2], o0.p[2], dot);
                dot = fdot2(h0.p[3], o0.p[3], dot);
                dot = fdot2(h1.p[0], o1.p[0], dot);
                dot = fdot2(h1.p[1], o1.p[1], dot);
                dot = fdot2(h1.p[2], o1.p[2], dot);
                dot = fdot2(h1.p[3], o1.p[3], dot);
                lgr[k] += dot;
                lg[b * LG_S + c] = (_Float16)lgr[k];
            });
        }
        __syncthreads();

        // ---- softmax over 32 capsules, one thread per input capsule c ----
        if (t < INC) {
            const int c = t;
            float m = -1e30f;
            for (int bb = 0; bb < NC; ++bb)
                m = fmaxf(m, (float)lg[bb * LG_S + c]);
            float S = 0.f;
            for (int bb = 0; bb < NC; ++bb) {
                float e = __expf((float)lg[bb * LG_S + c] - m);
                S += e;
                lg[bb * LG_S + c] = (_Float16)e;
            }
            float inv = 1.0f / S;
            for (int bb = 0; bb < NC; ++bb)
                lg[bb * LG_S + c] = (_Float16)((float)lg[bb * LG_S + c] * inv);
        }
        __syncthreads();

        // ---- S-pass from registers: s = sum_c cc[b][c] * hat[c][d] ----
        {
            const _Float16* cp = lg + b * LG_S;
            float sA = 0.f, sB = 0.f;
            sfor<18>([&](auto M) {
                constexpr int m2 = M.value;
                H8 cc;
                cc.v = *reinterpret_cast<const h8*>(cp + m2 * 8);
                sA = fdot2(cc.p[0], hreg[m2 * 4 + 0], sA);
                sB = fdot2(cc.p[1], hreg[m2 * 4 + 1], sB);
                sA = fdot2(cc.p[2], hreg[m2 * 4 + 2], sA);
                sB = fdot2(cc.p[3], hreg[m2 * 4 + 3], sB);
            });
            float oo = squash16(sA + sB);
            if (it == 0) {
                o_h[t] = (_Float16)oo;
            } else {
                out[(size_t)aout * (NC * DC) + t] = oo;
            }
        }
        if (it == 0) __syncthreads();
    }
}

template <typename WT>
__global__ __launch_bounds__(NT)
__attribute__((amdgpu_waves_per_eu(2, 2)))  // LDS pins us at 2 waves/SIMD: free the full 256-VGPR budget
void caps_kernel(const float* __restrict__ xg, const WT* __restrict__ Wg,
                 float* __restrict__ out) {
    extern __shared__ _Float16 sm[];
    _Float16* hat = sm;
    _Float16* lg = sm + LG_OFF;
    _Float16* o_h = sm + OH_OFF;
    _Float16* x_h = lg;  // overlap: x only live during phase H

    const int t = threadIdx.x;
    const int b = t >> 4;   // capsule
    const int d = t & 15;   // dim

    // ---- load x for 2 batch elems: 2304 floats = 576 f4, convert fp16 ----
    for (int i = t; i < (A2 * INC * IND) / 4; i += NT) {
        f4 v = reinterpret_cast<const f4*>(xg + (size_t)blockIdx.x * (A2 * INC * IND))[i];
        h4 h;
        h[0] = (_Float16)v[0]; h[1] = (_Float16)v[1];
        h[2] = (_Float16)v[2]; h[3] = (_Float16)v[3];
        *reinterpret_cast<h4*>(x_h + i * 4) = h;
    }
    __syncthreads();

    // ---- Phase H: hat for BOTH batch elements into registers; W loaded once ----
    h2 hA[72], hB[72];
    float s0A = 0.f, s0B = 0.f;
    {
        const WT* wp = Wg + ((size_t)(b * INC) * DC + d) * IND;
        const _Float16* xpA = x_h;
        const _Float16* xpB = x_h + INC * IND;
        sfor<INC>([&](auto C) {
            constexpr int c = C.value;
            H8 xa, xb;
            xa.v = *reinterpret_cast<const h8*>(xpA + c * IND);
            xb.v = *reinterpret_cast<const h8*>(xpB + c * IND);
            float accA, accB;
            if constexpr (sizeof(WT) == 2) {
                H8 wv;
                wv.v = *reinterpret_cast<const h8*>(wp + (size_t)c * (DC * IND));
                accA = fdot2(wv.p[0], xa.p[0], 0.f);
                accA = fdot2(wv.p[1], xa.p[1], accA);
                accA = fdot2(wv.p[2], xa.p[2], accA);
                accA = fdot2(wv.p[3], xa.p[3], accA);
                accB = fdot2(wv.p[0], xb.p[0], 0.f);
                accB = fdot2(wv.p[1], xb.p[1], accB);
                accB = fdot2(wv.p[2], xb.p[2], accB);
                accB = fdot2(wv.p[3], xb.p[3], accB);
            } else {
                const float* wf = reinterpret_cast<const float*>(wp) + (size_t)c * (DC * IND);
                f4 w0 = *reinterpret_cast<const f4*>(wf);
                f4 w1 = *reinterpret_cast<const f4*>(wf + 4);
                accA = (float)xa.v[0] * w0[0];
                accB = (float)xb.v[0] * w0[0];
                accA = fmaf((float)xa.v[1], w0[1], accA);
                accB = fmaf((float)xb.v[1], w0[1], accB);
                accA = fmaf((float)xa.v[2], w0[2], accA);
                accB = fmaf((float)xb.v[2], w0[2], accB);
                accA = fmaf((float)xa.v[3], w0[3], accA);
                accB = fmaf((float)xb.v[3], w0[3], accB);
                accA = fmaf((float)xa.v[4], w1[0], accA);
                accB = fmaf((float)xb.v[4], w1[0], accB);
                accA = fmaf((float)xa.v[5], w1[1], accA);
                accB = fmaf((float)xb.v[5], w1[1], accB);
                accA = fmaf((float)xa.v[6], w1[2], accA);
                accB = fmaf((float)xb.v[6], w1[2], accB);
                accA = fmaf((float)xa.v[7], w1[3], accA);
                accB = fmaf((float)xb.v[7], w1[3], accB);
            }
            s0A += accA;
            s0B += accB;
            hA[c >> 1][c & 1] = (_Float16)accA;  // RN convert = single source of truth
            hB[c >> 1][c & 1] = (_Float16)accB;
        });
    }
    const float oA = squash16(s0A * (1.0f / 32.0f));  // softmax(0) uniform -> s0 free
    const float oB = squash16(s0B * (1.0f / 32.0f));

    // ---- route a0 then a1 (shared LDS hat; publish syncs make the handoff safe) ----
    route_one(hA, oA, hat, lg, o_h, out, blockIdx.x * A2 + 0, t, b, d);
    route_one(hB, oB, hat, lg, o_h, out, blockIdx.x * A2 + 1, t, b, d);
}

extern "C" void kernel_launch(void* const* d_in, const int* in_sizes, int n_in,
                              void* d_out, int out_size, void* d_ws, size_t ws_size,
                              hipStream_t stream) {
    const float* x = (const float*)d_in[0];
    const float* W = (const float*)d_in[1];
    float* out = (float*)d_out;

    const size_t WH_BYTES = (size_t)NC * INC * DC * IND * 2;  // 1179648

    if (ws_size >= WH_BYTES) {
        _Float16* Wh = (_Float16*)d_ws;
        hipLaunchKernelGGL(convw_kernel, dim3((NC * INC * DC * IND / 4) / 256),
                           dim3(256), 0, stream, W, Wh);
        hipFuncSetAttribute(reinterpret_cast<const void*>(&caps_kernel<_Float16>),
                            hipFuncAttributeMaxDynamicSharedMemorySize, SMEM_BYTES);
        hipLaunchKernelGGL(caps_kernel<_Float16>, dim3(512 / A2), dim3(NT), SMEM_BYTES,
                           stream, x, Wh, out);
    } else {
        hipFuncSetAttribute(reinterpret_cast<const void*>(&caps_kernel<float>),
                            hipFuncAttributeMaxDynamicSharedMemorySize, SMEM_BYTES);
        hipLaunchKernelGGL(caps_kernel<float>, dim3(512 / A2), dim3(NT), SMEM_BYTES,
                           stream, x, W, out);
    }
}

// Round 8
// 53.537 us; speedup vs baseline: 1.5512x; 1.5512x over previous
//
#include <hip/hip_runtime.h>

#define NC 32     // num_capsule
#define DC 16     // dim_capsule
#define INC 144   // input capsules
#define IND 8     // input dim
#define NT 512    // threads per block

// ---- LDS layout (fp16 halves) ----
// hat split into two half-row arrays so every access pattern is conflict-free:
//   hatL[b][c][d=0..7], hatH[b][c][d=8..15]; 16B rows.
//   per-b stride 1168 halves = 584 dwords == 8 (mod 32): b-groups rotate bank quads.
//   HH base == 4 dwords (mod 32): H rows sit on the odd quads vs L rows.
// B-pass h8 row reads: lanes d=0..15 -> quads (8b+4d)%32: all 32 banks, 2-way = free.
// S-pass / H-phase scalar u16 column accesses: 2 lanes per dword, all banks = free.
#define HBS 1168                      // halves per b per half-array
#define HH_OFF (NC * HBS + 8)         // 37384; dword base % 32 == 4
#define LGW_OFF (HH_OFF + NC * HBS)   // 74760 (x_h overlaps this region during H)
#define LG_S 152
#define OH_OFF (LGW_OFF + NC * LG_S)  // 79624
#define SMEM_HALVES (OH_OFF + NC * DC) // 80136
#define SMEM_BYTES (SMEM_HALVES * 2)  // 160272 <= 163840

typedef _Float16 h2 __attribute__((ext_vector_type(2)));
typedef _Float16 h4 __attribute__((ext_vector_type(4)));
typedef _Float16 h8 __attribute__((ext_vector_type(8)));
typedef float f4 __attribute__((ext_vector_type(4)));

union H8 { h8 v; h2 p[4]; };

#if __has_builtin(__builtin_amdgcn_fdot2)
__device__ __forceinline__ float fdot2(h2 a, h2 b, float c) {
    return __builtin_amdgcn_fdot2(a, b, c, false);
}
#else
__device__ __forceinline__ float fdot2(h2 a, h2 b, float c) {
    return c + (float)a[0] * (float)b[0] + (float)a[1] * (float)b[1];
}
#endif

__global__ void convw_kernel(const float* __restrict__ W, _Float16* __restrict__ Wh) {
    int i = blockIdx.x * 256 + threadIdx.x;  // 147456 f4 groups
    f4 v = reinterpret_cast<const f4*>(W)[i];
    h4 h;
    h[0] = (_Float16)v[0]; h[1] = (_Float16)v[1];
    h[2] = (_Float16)v[2]; h[3] = (_Float16)v[3];
    reinterpret_cast<h4*>(Wh)[i] = h;
}

__device__ __forceinline__ float squash16(float s) {
    float n2 = s * s;
    n2 += __shfl_xor(n2, 1, 16);
    n2 += __shfl_xor(n2, 2, 16);
    n2 += __shfl_xor(n2, 4, 16);
    n2 += __shfl_xor(n2, 8, 16);
    return s * (n2 / ((1.0f + n2) * sqrtf(n2 + 1e-7f)));
}

template <typename WT>
__global__ __launch_bounds__(NT)
void caps_kernel(const float* __restrict__ xg, const WT* __restrict__ Wg,
                 float* __restrict__ out) {
    extern __shared__ _Float16 sm[];
    _Float16* lg = sm + LGW_OFF;
    _Float16* o_h = sm + OH_OFF;
    _Float16* x_h = lg;  // overlap: x only live during phase H

    const int t = threadIdx.x;
    const int b = t >> 4;   // capsule
    const int d = t & 15;   // dim
    const int a = blockIdx.x;

    // ---- load x[a]: 1152 floats = 288 f4, convert to fp16 ----
    if (t < (INC * IND) / 4) {
        f4 v = reinterpret_cast<const f4*>(xg + (size_t)a * (INC * IND))[t];
        h4 h;
        h[0] = (_Float16)v[0]; h[1] = (_Float16)v[1];
        h[2] = (_Float16)v[2]; h[3] = (_Float16)v[3];
        *reinterpret_cast<h4*>(x_h + t * 4) = h;
    }
    __syncthreads();

    // this thread's hat column base (write in H, read in S-pass); stride 8 halves per c
    _Float16* hw = sm + (d < 8 ? (b * HBS + d) : (HH_OFF + b * HBS + (d - 8)));

    // ---- Phase H: hat[b][c][d] = W[b,c,d,:] . x[c,:]; s0 falls out free ----
    float s0 = 0.0f;
    {
        const WT* wp = Wg + ((size_t)(b * INC) * DC + d) * IND;
        #pragma unroll 8
        for (int c = 0; c < INC; ++c) {
            H8 xv;
            xv.v = *reinterpret_cast<const h8*>(x_h + c * IND);
            float acc;
            if constexpr (sizeof(WT) == 2) {
                H8 wv;
                wv.v = *reinterpret_cast<const h8*>(wp + (size_t)c * (DC * IND));
                acc = fdot2(wv.p[0], xv.p[0], 0.f);
                acc = fdot2(wv.p[1], xv.p[1], acc);
                acc = fdot2(wv.p[2], xv.p[2], acc);
                acc = fdot2(wv.p[3], xv.p[3], acc);
            } else {
                const float* wf = reinterpret_cast<const float*>(wp) + (size_t)c * (DC * IND);
                f4 w0 = *reinterpret_cast<const f4*>(wf);
                f4 w1 = *reinterpret_cast<const f4*>(wf + 4);
                acc = (float)xv.v[0] * w0[0];
                acc = fmaf((float)xv.v[1], w0[1], acc);
                acc = fmaf((float)xv.v[2], w0[2], acc);
                acc = fmaf((float)xv.v[3], w0[3], acc);
                acc = fmaf((float)xv.v[4], w1[0], acc);
                acc = fmaf((float)xv.v[5], w1[1], acc);
                acc = fmaf((float)xv.v[6], w1[2], acc);
                acc = fmaf((float)xv.v[7], w1[3], acc);
            }
            s0 += acc;
            hw[c * 8] = (_Float16)acc;  // scalar u16, conflict-free by layout
            (void)0;
        }
    }
    {
        float o0 = squash16(s0 * (1.0f / 32.0f));  // softmax(0) uniform
        o_h[t] = (_Float16)o0;
    }
    __syncthreads();  // hat + o visible; x_h region now dead

    float lgr[9] = {0.f, 0.f, 0.f, 0.f, 0.f, 0.f, 0.f, 0.f, 0.f};  // fp32 logit master

    for (int it = 0; it < 2; ++it) {
        // ---- B-pass: logit[b][c] += o[b,:] . hat[b][c][:], c = d + 16k ----
        {
            H8 oL, oH;
            oL.v = *reinterpret_cast<const h8*>(o_h + b * DC);
            oH.v = *reinterpret_cast<const h8*>(o_h + b * DC + 8);
            #pragma unroll
            for (int k = 0; k < 9; ++k) {
                const int c = d + DC * k;
                H8 hl, hh;
                hl.v = *reinterpret_cast<const h8*>(sm + b * HBS + c * 8);
                hh.v = *reinterpret_cast<const h8*>(sm + HH_OFF + b * HBS + c * 8);
                float dot = fdot2(hl.p[0], oL.p[0], 0.f);
                dot = fdot2(hl.p[1], oL.p[1], dot);
                dot = fdot2(hl.p[2], oL.p[2], dot);
                dot = fdot2(hl.p[3], oL.p[3], dot);
                dot = fdot2(hh.p[0], oH.p[0], dot);
                dot = fdot2(hh.p[1], oH.p[1], dot);
                dot = fdot2(hh.p[2], oH.p[2], dot);
                dot = fdot2(hh.p[3], oH.p[3], dot);
                lgr[k] += dot;
                lg[b * LG_S + c] = (_Float16)lgr[k];
            }
        }
        __syncthreads();

        // ---- softmax over 32 capsules, one thread per input capsule c ----
        if (t < INC) {
            const int c = t;
            float m = -1e30f;
            for (int bb = 0; bb < NC; ++bb)
                m = fmaxf(m, (float)lg[bb * LG_S + c]);
            float S = 0.f;
            for (int bb = 0; bb < NC; ++bb) {
                float e = __expf((float)lg[bb * LG_S + c] - m);
                S += e;
                lg[bb * LG_S + c] = (_Float16)e;
            }
            float inv = 1.0f / S;
            for (int bb = 0; bb < NC; ++bb)
                lg[bb * LG_S + c] = (_Float16)((float)lg[bb * LG_S + c] * inv);
        }
        __syncthreads();

        // ---- S-pass: s = sum_c cc[b][c] * hat[b][c][d] (scalar LDS, conflict-free) ----
        {
            const _Float16* cp = lg + b * LG_S;
            float s = 0.f;
            #pragma unroll 8
            for (int c = 0; c < INC; ++c)
                s = fmaf((float)cp[c], (float)hw[c * 8], s);
            float oo = squash16(s);
            if (it == 0) {
                o_h[t] = (_Float16)oo;
            } else {
                out[(size_t)a * (NC * DC) + t] = oo;
            }
        }
        if (it == 0) __syncthreads();
    }
}

extern "C" void kernel_launch(void* const* d_in, const int* in_sizes, int n_in,
                              void* d_out, int out_size, void* d_ws, size_t ws_size,
                              hipStream_t stream) {
    const float* x = (const float*)d_in[0];
    const float* W = (const float*)d_in[1];
    float* out = (float*)d_out;

    const size_t WH_BYTES = (size_t)NC * INC * DC * IND * 2;  // 1179648

    if (ws_size >= WH_BYTES) {
        _Float16* Wh = (_Float16*)d_ws;
        hipLaunchKernelGGL(convw_kernel, dim3((NC * INC * DC * IND / 4) / 256),
                           dim3(256), 0, stream, W, Wh);
        hipFuncSetAttribute(reinterpret_cast<const void*>(&caps_kernel<_Float16>),
                            hipFuncAttributeMaxDynamicSharedMemorySize, SMEM_BYTES);
        hipLaunchKernelGGL(caps_kernel<_Float16>, dim3(512), dim3(NT), SMEM_BYTES,
                           stream, x, Wh, out);
    } else {
        hipFuncSetAttribute(reinterpret_cast<const void*>(&caps_kernel<float>),
                            hipFuncAttributeMaxDynamicSharedMemorySize, SMEM_BYTES);
        hipLaunchKernelGGL(caps_kernel<float>, dim3(512), dim3(NT), SMEM_BYTES,
                           stream, x, W, out);
    }
}

// Round 9
// 52.818 us; speedup vs baseline: 1.5723x; 1.0136x over previous
//
#include <hip/hip_runtime.h>

#define NC 32     // num_capsule
#define DC 16     // dim_capsule
#define INC 144   // input capsules
#define IND 8     // input dim
#define NT 1024   // 16 waves: 4/SIMD (LDS still limits to 1 block/CU)

// ---- LDS layout (fp16 halves) ----
// hatL[b][c][d0..7] / hatH[b][c][d8..15]: 16B rows, per-b stride 1168 halves
//   (584 dw == 8 mod 32 -> b-groups on disjoint quads); HH base dw%32 == 4.
// lg_T[c][bb]: TRANSPOSED logits, stride 36 halves (18 dw -> b64 reads spread
//   evenly over all banks). x_h overlays lg_T during phase H (dead after).
// o_h[32][16] fp16 | ps[512] fp32 half-partials.
#define HBS 1168
#define HH_OFF (NC * HBS + 8)            // 37384
#define LGT_OFF (HH_OFF + NC * HBS)      // 74760
#define LGT_S 36
#define OH_OFF (LGT_OFF + INC * LGT_S)   // 79944
#define PS_OFF (OH_OFF + NC * DC)        // 80456 (halves; byte offset %4 == 0)
#define SMEM_HALVES (PS_OFF + 512 * 2)   // 81480
#define SMEM_BYTES (SMEM_HALVES * 2)     // 162960 <= 163840

typedef _Float16 h2 __attribute__((ext_vector_type(2)));
typedef _Float16 h4 __attribute__((ext_vector_type(4)));
typedef _Float16 h8 __attribute__((ext_vector_type(8)));
typedef float f4 __attribute__((ext_vector_type(4)));

union H8 { h8 v; h2 p[4]; };

#if __has_builtin(__builtin_amdgcn_fdot2)
__device__ __forceinline__ float fdot2(h2 a, h2 b, float c) {
    return __builtin_amdgcn_fdot2(a, b, c, false);
}
#else
__device__ __forceinline__ float fdot2(h2 a, h2 b, float c) {
    return c + (float)a[0] * (float)b[0] + (float)a[1] * (float)b[1];
}
#endif

__global__ void convw_kernel(const float* __restrict__ W, _Float16* __restrict__ Wh) {
    int i = blockIdx.x * 256 + threadIdx.x;  // 147456 f4 groups
    f4 v = reinterpret_cast<const f4*>(W)[i];
    h4 h;
    h[0] = (_Float16)v[0]; h[1] = (_Float16)v[1];
    h[2] = (_Float16)v[2]; h[3] = (_Float16)v[3];
    reinterpret_cast<h4*>(Wh)[i] = h;
}

__device__ __forceinline__ float squash16(float s) {
    float n2 = s * s;
    n2 += __shfl_xor(n2, 1, 16);
    n2 += __shfl_xor(n2, 2, 16);
    n2 += __shfl_xor(n2, 4, 16);
    n2 += __shfl_xor(n2, 8, 16);
    return s * (n2 / ((1.0f + n2) * sqrtf(n2 + 1e-7f)));
}

template <typename WT>
__global__ __launch_bounds__(NT, 4)  // 4 waves/EU min -> VGPR <= 128 (no spill at ~60 live)
void caps_kernel(const float* __restrict__ xg, const WT* __restrict__ Wg,
                 float* __restrict__ out) {
    extern __shared__ _Float16 sm[];
    _Float16* lg = sm + LGT_OFF;   // lg_T[c][bb], stride LGT_S
    _Float16* o_h = sm + OH_OFF;
    float* ps = reinterpret_cast<float*>(sm + PS_OFF);
    _Float16* x_h = lg;            // overlap: x only live during phase H

    const int t = threadIdx.x;
    const int h = t >> 9;     // half: which 72 c's this thread owns
    const int u = t & 511;
    const int b = u >> 4;     // capsule
    const int d = u & 15;     // dim
    const int a = blockIdx.x;
    const int c0 = h * 72;

    // ---- load x[a]: 1152 floats = 288 f4, convert to fp16 ----
    if (t < (INC * IND) / 4) {
        f4 v = reinterpret_cast<const f4*>(xg + (size_t)a * (INC * IND))[t];
        h4 hv;
        hv[0] = (_Float16)v[0]; hv[1] = (_Float16)v[1];
        hv[2] = (_Float16)v[2]; hv[3] = (_Float16)v[3];
        *reinterpret_cast<h4*>(x_h + t * 4) = hv;
    }
    __syncthreads();

    // this thread's hat column base (write in H, read in S-pass); stride 8 halves/c
    _Float16* hw = sm + (d < 8 ? (b * HBS + d) : (HH_OFF + b * HBS + (d - 8)));

    // ---- Phase H (split): hat[b][c][d] for c in [c0, c0+72) ----
    float s0 = 0.0f;
    {
        const WT* wp = Wg + ((size_t)(b * INC + c0) * DC + d) * IND;
        #pragma unroll 8
        for (int c = c0; c < c0 + 72; ++c) {
            H8 xv;
            xv.v = *reinterpret_cast<const h8*>(x_h + c * IND);
            float acc;
            if constexpr (sizeof(WT) == 2) {
                H8 wv;
                wv.v = *reinterpret_cast<const h8*>(wp);
                acc = fdot2(wv.p[0], xv.p[0], 0.f);
                acc = fdot2(wv.p[1], xv.p[1], acc);
                acc = fdot2(wv.p[2], xv.p[2], acc);
                acc = fdot2(wv.p[3], xv.p[3], acc);
            } else {
                const float* wf = reinterpret_cast<const float*>(wp);
                f4 w0 = *reinterpret_cast<const f4*>(wf);
                f4 w1 = *reinterpret_cast<const f4*>(wf + 4);
                acc = (float)xv.v[0] * w0[0];
                acc = fmaf((float)xv.v[1], w0[1], acc);
                acc = fmaf((float)xv.v[2], w0[2], acc);
                acc = fmaf((float)xv.v[3], w0[3], acc);
                acc = fmaf((float)xv.v[4], w1[0], acc);
                acc = fmaf((float)xv.v[5], w1[1], acc);
                acc = fmaf((float)xv.v[6], w1[2], acc);
                acc = fmaf((float)xv.v[7], w1[3], acc);
            }
            wp += DC * IND;
            s0 += acc;
            hw[c * 8] = (_Float16)acc;  // scalar u16, conflict-light by layout
        }
    }
    // combine s0 halves through ps, squash -> o_h (softmax(0) uniform)
    if (h) ps[u] = s0;
    __syncthreads();
    if (!h) {
        float s0t = s0 + ps[u];
        o_h[u] = (_Float16)squash16(s0t * (1.0f / 32.0f));
    }
    __syncthreads();

    const int NK = h ? 4 : 5;        // B-pass k-range split: k = h + 2q
    float lgr[5] = {0.f, 0.f, 0.f, 0.f, 0.f};  // fp32 logit master

    for (int it = 0; it < 2; ++it) {
        // ---- B-pass: logit[b][c] += o[b,:] . hat[b][c][:], c = d + 16(h+2q) ----
        {
            H8 oL, oH;
            oL.v = *reinterpret_cast<const h8*>(o_h + b * DC);
            oH.v = *reinterpret_cast<const h8*>(o_h + b * DC + 8);
            #pragma unroll
            for (int q = 0; q < 5; ++q) {
                if (q < NK) {  // wave-uniform
                    const int c = d + DC * (h + 2 * q);
                    H8 hl, hu;
                    hl.v = *reinterpret_cast<const h8*>(sm + b * HBS + c * 8);
                    hu.v = *reinterpret_cast<const h8*>(sm + HH_OFF + b * HBS + c * 8);
                    float dot = fdot2(hl.p[0], oL.p[0], 0.f);
                    dot = fdot2(hl.p[1], oL.p[1], dot);
                    dot = fdot2(hl.p[2], oL.p[2], dot);
                    dot = fdot2(hl.p[3], oL.p[3], dot);
                    dot = fdot2(hu.p[0], oH.p[0], dot);
                    dot = fdot2(hu.p[1], oH.p[1], dot);
                    dot = fdot2(hu.p[2], oH.p[2], dot);
                    dot = fdot2(hu.p[3], oH.p[3], dot);
                    lgr[q] += dot;
                    lg[c * LGT_S + b] = (_Float16)lgr[q];
                }
            }
        }
        __syncthreads();

        // ---- softmax over 32 capsules: 2 threads per c, 16 bb's each ----
        if (t < 2 * INC) {
            const int c = t >> 1;
            const int hh = t & 1;
            _Float16* row = lg + c * LGT_S + hh * 16;
            float v[16];
            #pragma unroll
            for (int j = 0; j < 4; ++j) {
                h4 r = *reinterpret_cast<const h4*>(row + 4 * j);
                v[4 * j + 0] = (float)r[0]; v[4 * j + 1] = (float)r[1];
                v[4 * j + 2] = (float)r[2]; v[4 * j + 3] = (float)r[3];
            }
            float m = v[0];
            #pragma unroll
            for (int j = 1; j < 16; ++j) m = fmaxf(m, v[j]);
            m = fmaxf(m, __shfl_xor(m, 1));
            float S = 0.f;
            #pragma unroll
            for (int j = 0; j < 16; ++j) { v[j] = __expf(v[j] - m); S += v[j]; }
            S += __shfl_xor(S, 1);
            float inv = 1.0f / S;
            #pragma unroll
            for (int j = 0; j < 4; ++j) {
                h4 r;
                r[0] = (_Float16)(v[4 * j + 0] * inv);
                r[1] = (_Float16)(v[4 * j + 1] * inv);
                r[2] = (_Float16)(v[4 * j + 2] * inv);
                r[3] = (_Float16)(v[4 * j + 3] * inv);
                *reinterpret_cast<h4*>(row + 4 * j) = r;
            }
        }
        __syncthreads();

        // ---- S-pass (split): s = sum_{c in half} cc[b][c] * hat[b][c][d] ----
        {
            const _Float16* cp0 = lg + b;  // cc[c] = lg_T[c][b], broadcast per b-group
            float s = 0.f;
            #pragma unroll 8
            for (int c = c0; c < c0 + 72; ++c)
                s = fmaf((float)cp0[c * LGT_S], (float)hw[c * 8], s);
            if (h) ps[u] = s;
            __syncthreads();
            if (!h) {
                float st = s + ps[u];
                float oo = squash16(st);
                if (it == 0) o_h[u] = (_Float16)oo;
                else out[(size_t)a * (NC * DC) + u] = oo;
            }
            if (it == 0) __syncthreads();
        }
    }
}

extern "C" void kernel_launch(void* const* d_in, const int* in_sizes, int n_in,
                              void* d_out, int out_size, void* d_ws, size_t ws_size,
                              hipStream_t stream) {
    const float* x = (const float*)d_in[0];
    const float* W = (const float*)d_in[1];
    float* out = (float*)d_out;

    const size_t WH_BYTES = (size_t)NC * INC * DC * IND * 2;  // 1179648

    if (ws_size >= WH_BYTES) {
        _Float16* Wh = (_Float16*)d_ws;
        hipLaunchKernelGGL(convw_kernel, dim3((NC * INC * DC * IND / 4) / 256),
                           dim3(256), 0, stream, W, Wh);
        hipFuncSetAttribute(reinterpret_cast<const void*>(&caps_kernel<_Float16>),
                            hipFuncAttributeMaxDynamicSharedMemorySize, SMEM_BYTES);
        hipLaunchKernelGGL(caps_kernel<_Float16>, dim3(512), dim3(NT), SMEM_BYTES,
                           stream, x, Wh, out);
    } else {
        hipFuncSetAttribute(reinterpret_cast<const void*>(&caps_kernel<float>),
                            hipFuncAttributeMaxDynamicSharedMemorySize, SMEM_BYTES);
        hipLaunchKernelGGL(caps_kernel<float>, dim3(512), dim3(NT), SMEM_BYTES,
                           stream, x, W, out);
    }
}